// Round 7
// baseline (185.175 us; speedup 1.0000x reference)
//
#include <hip/hip_runtime.h>
#include <stdint.h>

typedef unsigned short ushort_t;
typedef __attribute__((ext_vector_type(8))) short short8;   // 8 x bf16 (4 VGPRs)
typedef __attribute__((ext_vector_type(4))) float floatx4;  // MFMA accum

#define SEQ_N 2048
#define SEQ_M 2048
#define DIM_D 128
#define DIM_V 128
#define BC 64

// LDS (ushort elems), single-buffered: 44544 B -> 3 wgs/CU (133632 <= 163840)
#define KS_LD 136
#define VS_LD 72
#define PS_LD 68
#define K0 0
#define V0 8704
#define P0 17920            // 8704 + 128*72
#define SMEM_ELEMS 22272    // + 4*16*68

// ws: ML[16][72][2][64] fp32, then Obf[16][48][64][128] bf16 = 13,172,736 B
#define ML_FLOATS (16 * 72 * 2 * 64)
#define WS_BYTES  ((size_t)ML_FLOATS * 4 + (size_t)16 * 48 * 64 * 128 * 2)

#if __has_builtin(__builtin_amdgcn_exp2f)
#define EXP2F(x) __builtin_amdgcn_exp2f(x)
#else
#define EXP2F(x) exp2f(x)
#endif

template <int CTRL>
__device__ __forceinline__ float dpp_f(float x) {
  int xi = __builtin_bit_cast(int, x);
  int yi = __builtin_amdgcn_update_dpp(xi, xi, CTRL, 0xf, 0xf, false);
  return __builtin_bit_cast(float, yi);
}
__device__ __forceinline__ float rowmax16(float x) {
  x = fmaxf(x, dpp_f<0x128>(x));
  x = fmaxf(x, dpp_f<0x124>(x));
  x = fmaxf(x, dpp_f<0x122>(x));
  x = fmaxf(x, dpp_f<0x121>(x));
  return x;
}
__device__ __forceinline__ float rowsum16(float x) {
  x += dpp_f<0x128>(x);
  x += dpp_f<0x124>(x);
  x += dpp_f<0x122>(x);
  x += dpp_f<0x121>(x);
  return x;
}

__device__ __forceinline__ ushort_t f2bf(float f) {
  uint32_t u = __builtin_bit_cast(uint32_t, f);
  return (ushort_t)((u + 0x8000u) >> 16);
}
__device__ __forceinline__ uint32_t bfpack(float lo, float hi) {
  uint32_t a = __builtin_bit_cast(uint32_t, lo) + 0x8000u;
  uint32_t b = __builtin_bit_cast(uint32_t, hi) + 0x8000u;
  return __builtin_amdgcn_perm(b, a, 0x07060302u);
}
__device__ __forceinline__ float bf2f(uint32_t u16) {
  return __builtin_bit_cast(float, u16 << 16);
}

// One flash chunk over Q rows [rt*64, rt*64+64), key tiles [jt_lo, jt_hi).
// nch==1: normalized store to Out. Else: self-normalized partial; oidx<0 -> Out
// (fp32, chunk 0), oidx>=0 -> bf16 ws slot; (m,l) always to ws ML slot.
__device__ __forceinline__ void process_chunk(
    const float* __restrict__ Q, const float* __restrict__ K,
    const float* __restrict__ Vg, float* __restrict__ Out,
    float* __restrict__ ws, ushort_t* __restrict__ smem,
    int b, int rt, int jt_lo, int jt_hi, int mlimit, int flag,
    int nch, int slot, int oidx) {
  const int tid  = threadIdx.x;
  const int lane = tid & 63;
  const int w    = tid >> 6;
  const int qd   = lane >> 4;
  const int nn   = lane & 15;

  const float c1 = 0.08838834764831845f * 1.4426950408889634f;  // scale*log2e

  const int oct = tid & 15;
  const int j0  = (tid >> 4) * 4;
  const int hh  = nn >> 3;
  const int rb  = 8 * hh;

  const int i0w = rt * 64 + w * 16;
  const size_t koff = (size_t)b * SEQ_M * DIM_D;
  const size_t voff = (size_t)b * SEQ_M * DIM_V;

  // ---- Q fragments, pre-scaled by c1 (folds softmax scale into QK) ----
  short8 qf[4];
  {
    const float* Qb = Q + ((size_t)b * SEQ_N + (size_t)(i0w + nn)) * DIM_D;
    union { short8 v; uint32_t u32[4]; } t;
#pragma unroll
    for (int ks = 0; ks < 4; ++ks) {
      const float* p = Qb + ks * 32 + qd * 8;
      float4 f0 = *(const float4*)p, f1 = *(const float4*)(p + 4);
      t.u32[0] = bfpack(f0.x * c1, f0.y * c1);
      t.u32[1] = bfpack(f0.z * c1, f0.w * c1);
      t.u32[2] = bfpack(f1.x * c1, f1.y * c1);
      t.u32[3] = bfpack(f1.z * c1, f1.w * c1);
      qf[ks] = t.v;
    }
  }

  floatx4 o[8];
#pragma unroll
  for (int vt = 0; vt < 8; ++vt) o[vt] = (floatx4)0.0f;
  float m[4], l[4];
#pragma unroll
  for (int r = 0; r < 4; ++r) { m[r] = -3.0e38f; l[r] = 0.0f; }

  float4 kr[4][2], vr[4][2];   // register prefetch

  auto stage_load = [&](int jt) {
    const int jbase = jt * BC;
#pragma unroll
    for (int r = 0; r < 4; ++r) {
      const float* kp = K  + koff + (size_t)(jbase + j0 + r) * DIM_D + oct * 8;
      kr[r][0] = *(const float4*)kp;  kr[r][1] = *(const float4*)(kp + 4);
      const float* vp = Vg + voff + (size_t)(jbase + j0 + r) * DIM_V + oct * 8;
      vr[r][0] = *(const float4*)vp;  vr[r][1] = *(const float4*)(vp + 4);
    }
  };

  auto stage_write = [&](int jt) {
    const int jbase = jt * BC;
#pragma unroll
    for (int r = 0; r < 4; ++r) {     // K rows, zero padded keys
      uint4 kw;
      kw.x = bfpack(kr[r][0].x, kr[r][0].y);
      kw.y = bfpack(kr[r][0].z, kr[r][0].w);
      kw.z = bfpack(kr[r][1].x, kr[r][1].y);
      kw.w = bfpack(kr[r][1].z, kr[r][1].w);
      if (jbase + j0 + r >= mlimit) kw = make_uint4(0u, 0u, 0u, 0u);
      *(uint4*)(smem + K0 + (j0 + r) * KS_LD + oct * 8) = kw;
    }
    float vc[4][8];
#pragma unroll
    for (int r = 0; r < 4; ++r) {
      vc[r][0]=vr[r][0].x; vc[r][1]=vr[r][0].y; vc[r][2]=vr[r][0].z; vc[r][3]=vr[r][0].w;
      vc[r][4]=vr[r][1].x; vc[r][5]=vr[r][1].y; vc[r][6]=vr[r][1].z; vc[r][7]=vr[r][1].w;
    }
#pragma unroll
    for (int q = 0; q < 8; ++q) {
      const int p = 8 * oct + ((oct + q) & 7);   // bijective V^T row swizzle
      uint2 dv;
      dv.x = bfpack(vc[0][q], vc[1][q]);
      dv.y = bfpack(vc[2][q], vc[3][q]);
      *(uint2*)(smem + V0 + p * VS_LD + j0) = dv;
    }
  };

  stage_load(jt_lo);
  stage_write(jt_lo);
  __syncthreads();

  const int len = jt_hi - jt_lo;
#pragma unroll 1
  for (int t = 0; t < len; ++t) {
    const int jt = jt_lo + t;
    const bool more = (t + 1) < len;
    const int jbase = jt * BC;
    if (more) stage_load(jt + 1);

    // ---- S = Q K^T ----
    floatx4 s[4];
#pragma unroll
    for (int ct = 0; ct < 4; ++ct) s[ct] = (floatx4)0.0f;
#pragma unroll
    for (int ks = 0; ks < 4; ++ks) {
#pragma unroll
      for (int ct = 0; ct < 4; ++ct) {
        short8 bf = *(const short8*)(smem + K0 + (ct * 16 + nn) * KS_LD + ks * 32 + qd * 8);
        s[ct] = __builtin_amdgcn_mfma_f32_16x16x32_bf16(qf[ks], bf, s[ct], 0, 0, 0);
      }
    }

    // ---- online softmax ----
    {
      float tt[4][4];
      if (flag && (jbase + BC - 1 > i0w)) {
#pragma unroll
        for (int ct = 0; ct < 4; ++ct)
#pragma unroll
          for (int r = 0; r < 4; ++r) {
            float tv = s[ct][r];
            if (jbase + ct * 16 + nn > i0w + qd * 4 + r) tv = -3.0e38f;
            tt[ct][r] = tv;
          }
      } else {
#pragma unroll
        for (int ct = 0; ct < 4; ++ct)
#pragma unroll
          for (int r = 0; r < 4; ++r) tt[ct][r] = s[ct][r];
      }
      float mn[4];
#pragma unroll
      for (int r = 0; r < 4; ++r) {
        float mr = fmaxf(fmaxf(tt[0][r], tt[1][r]), fmaxf(tt[2][r], tt[3][r]));
        mr = rowmax16(mr);
        mn[r] = fmaxf(m[r], mr);
      }
      int same = (mn[0] == m[0]) && (mn[1] == m[1]) && (mn[2] == m[2]) && (mn[3] == m[3]);
      if (!__all(same)) {   // wave-uniform: rescale only when some max moved
#pragma unroll
        for (int r = 0; r < 4; ++r) {
          float alpha = EXP2F(m[r] - mn[r]);
          l[r] *= alpha;
#pragma unroll
          for (int vt = 0; vt < 8; ++vt) o[vt][r] *= alpha;
        }
      }
#pragma unroll
      for (int r = 0; r < 4; ++r) {
        m[r] = mn[r];
        float ps = 0.0f;
#pragma unroll
        for (int ct = 0; ct < 4; ++ct) {
          float p = EXP2F(tt[ct][r] - m[r]);
          tt[ct][r] = p;
          ps += p;
        }
        l[r] += ps;
      }
#pragma unroll
      for (int ct = 0; ct < 4; ++ct)
#pragma unroll
        for (int r = 0; r < 4; ++r)
          smem[P0 + (w * 16 + qd * 4 + r) * PS_LD + ct * 16 + nn] = f2bf(tt[ct][r]);
    }

    // ---- O += P V ----
#pragma unroll
    for (int ks2 = 0; ks2 < 2; ++ks2) {
      short8 a = *(const short8*)(smem + P0 + (w * 16 + nn) * PS_LD + ks2 * 32 + qd * 8);
#pragma unroll
      for (int vt = 0; vt < 8; ++vt) {
        const int p = 16 * vt + rb + ((2 * vt + nn + hh) & 7);
        short8 vbf = *(const short8*)(smem + V0 + p * VS_LD + ks2 * 32 + qd * 8);
        o[vt] = __builtin_amdgcn_mfma_f32_16x16x32_bf16(a, vbf, o[vt], 0, 0, 0);
      }
    }

    __syncthreads();                       // all waves done reading K/V
    if (more) { stage_write(jt + 1); __syncthreads(); }
  }

#pragma unroll
  for (int r = 0; r < 4; ++r) l[r] = rowsum16(l[r]);

  // ---- epilogue: self-normalized output; (m,l) to ws for split tiles ----
  if (nch > 1) {
    float* mlp = ws + (size_t)(b * 72 + slot) * 2 * 64;
    if (nn == 0) {
#pragma unroll
      for (int r = 0; r < 4; ++r) {
        int row = w * 16 + qd * 4 + r;
        mlp[row]      = m[r];
        mlp[64 + row] = l[r];
      }
    }
  }
  if (nch == 1 || oidx < 0) {
    float* Ob = Out + ((size_t)b * SEQ_N + i0w) * DIM_V;
#pragma unroll
    for (int r = 0; r < 4; ++r) {
      float inv = 1.0f / l[r];
      int row = qd * 4 + r;
#pragma unroll
      for (int vt = 0; vt < 8; ++vt)
        Ob[(size_t)row * DIM_V + vt * 16 + nn] = o[vt][r] * inv;
    }
  } else {
    ushort_t* ob = (ushort_t*)(ws + ML_FLOATS) + (size_t)(b * 48 + oidx) * 64 * 128;
#pragma unroll
    for (int r = 0; r < 4; ++r) {
      float inv = 1.0f / l[r];
      int row = w * 16 + qd * 4 + r;
#pragma unroll
      for (int vt = 0; vt < 8; ++vt)
        ob[row * 128 + vt * 16 + nn] = f2bf(o[vt][r] * inv);
    }
  }
}

// mode 1: 1280 chunk wgs (<=8 tiles), LPT order. mode 0 (no-ws fallback): 512 whole rows.
__global__ __launch_bounds__(256, 3)
void fa_chunk(const float* __restrict__ Q, const float* __restrict__ K,
              const float* __restrict__ Vg, const int* __restrict__ kpl,
              const int* __restrict__ amask, float* __restrict__ Out,
              float* __restrict__ ws, int mode) {
  __shared__ __align__(16) ushort_t smem[SMEM_ELEMS];
  const int u = blockIdx.x;
  const int b = u & 15;
  const int idx = u >> 4;
  const int flag = amask[0];
  const int mlimit = SEQ_M - kpl[b];

  if (mode == 0) {
    int rt = 31 - idx;
    int hi = flag ? (rt + 1) : (SEQ_M / BC);
    process_chunk(Q, K, Vg, Out, ws, smem, b, rt, 0, hi, mlimit, flag, 1, 0, -1);
    return;
  }
  if (flag) {
    int rt, c, nch;
    if (idx < 32)      { rt = 31 - (idx >> 2); c = idx & 3; nch = 4; }
    else if (idx < 56) { int t = idx - 32; int q3 = t / 3; rt = 23 - q3; c = t - 3 * q3; nch = 3; }
    else if (idx < 72) { int t = idx - 56; rt = 15 - (t >> 1); c = t & 1; nch = 2; }
    else               { rt = 79 - idx; c = 0; nch = 1; }
    const int tiles = rt + 1;
    const int lo = (c * tiles) / nch, hi = ((c + 1) * tiles) / nch;
    int slot = 0, oidx = -1;
    if (nch > 1) {
      int sb = (rt >= 24) ? 40 + (rt - 24) * 4 : (rt >= 16) ? 16 + (rt - 16) * 3 : (rt - 8) * 2;
      slot = sb + c;
      if (c > 0)
        oidx = (rt >= 24) ? 24 + (rt - 24) * 3 + (c - 1)
             : (rt >= 16) ? 8 + (rt - 16) * 2 + (c - 1)
                          : (rt - 8) + (c - 1);
    }
    process_chunk(Q, K, Vg, Out, ws, smem, b, rt, lo, hi, mlimit, flag, nch, slot, oidx);
  } else {
    if (u >= 1024) return;
    const int rt = 31 - (idx >> 1), c = idx & 1;
    process_chunk(Q, K, Vg, Out, ws, smem, b, rt, c * 16, c * 16 + 16, mlimit, 0,
                  2, rt * 2 + c, (c > 0) ? rt : -1);
  }
}

__global__ __launch_bounds__(256)
void fa_merge(float* __restrict__ ws, float* __restrict__ Out,
              const int* __restrict__ amask) {
  const int flag = amask[0];
  const int w = threadIdx.x >> 6, lane = threadIdx.x & 63;
  const int rid = blockIdx.x * 4 + w;
  int b, rt, row, nch, sb, ob;
  if (flag) {
    if (rid >= 24576) return;
    b = rid / 1536; int rr = rid - b * 1536;
    rt = 8 + (rr >> 6); row = rr & 63;
    nch = (rt >= 24) ? 4 : (rt >= 16) ? 3 : 2;
    sb  = (rt >= 24) ? 40 + (rt - 24) * 4 : (rt >= 16) ? 16 + (rt - 16) * 3 : (rt - 8) * 2;
    ob  = (rt >= 24) ? 24 + (rt - 24) * 3 : (rt >= 16) ? 8 + (rt - 16) * 2 : (rt - 8);
  } else {
    if (rid >= 32768) return;
    b = rid >> 11; int rr = rid & 2047;
    rt = rr >> 6; row = rr & 63;
    nch = 2; sb = rt * 2; ob = rt;
  }
  float mm[4], ll[4];
  float M = -3.0e38f;
#pragma unroll
  for (int cc = 0; cc < 4; ++cc) if (cc < nch) {
    const float* mlp = ws + (size_t)(b * 72 + sb + cc) * 2 * 64;
    mm[cc] = mlp[row];
    ll[cc] = mlp[64 + row];
    M = fmaxf(M, mm[cc]);
  }
  float wc[4], wsum = 0.0f;
#pragma unroll
  for (int cc = 0; cc < 4; ++cc) if (cc < nch) {
    wc[cc] = ll[cc] * EXP2F(mm[cc] - M);
    wsum += wc[cc];
  }
  const float inv = 1.0f / wsum;
  float* orow = Out + ((size_t)b * SEQ_N + rt * 64 + row) * DIM_V;
  float2 acc = *(float2*)(orow + lane * 2);
  acc.x *= wc[0]; acc.y *= wc[0];
  const ushort_t* Obf = (const ushort_t*)(ws + ML_FLOATS);
#pragma unroll
  for (int cc = 1; cc < 4; ++cc) if (cc < nch) {
    const ushort_t* pr = Obf + ((size_t)(b * 48 + ob + cc - 1) * 64 + row) * 128;
    uint32_t v = *(const uint32_t*)(pr + lane * 2);
    acc.x += bf2f(v & 0xffffu) * wc[cc];
    acc.y += bf2f(v >> 16)     * wc[cc];
  }
  acc.x *= inv; acc.y *= inv;
  *(float2*)(orow + lane * 2) = acc;
}

extern "C" void kernel_launch(void* const* d_in, const int* in_sizes, int n_in,
                              void* d_out, int out_size, void* d_ws, size_t ws_size,
                              hipStream_t stream) {
  const float* Q   = (const float*)d_in[0];
  const float* K   = (const float*)d_in[1];
  const float* V   = (const float*)d_in[2];
  const int* kpl   = (const int*)d_in[3];
  const int* amask = (const int*)d_in[4];
  float* O         = (float*)d_out;
  float* ws        = (float*)d_ws;

  if (ws_size >= WS_BYTES) {
    hipLaunchKernelGGL(fa_chunk, dim3(1280), dim3(256), 0, stream, Q, K, V, kpl, amask, O, ws, 1);
    hipLaunchKernelGGL(fa_merge, dim3(8192), dim3(256), 0, stream, ws, O, amask);
  } else {
    hipLaunchKernelGGL(fa_chunk, dim3(512), dim3(256), 0, stream, Q, K, V, kpl, amask, O, ws, 0);
  }
}

// Round 8
// 165.802 us; speedup vs baseline: 1.1168x; 1.1168x over previous
//
#include <hip/hip_runtime.h>
#include <stdint.h>

typedef unsigned short ushort_t;
typedef __attribute__((ext_vector_type(8))) short short8;   // 8 x bf16 (4 VGPRs)
typedef __attribute__((ext_vector_type(4))) float floatx4;  // MFMA accum

#define SEQ_N 2048
#define SEQ_M 2048
#define DIM_D 128
#define DIM_V 128
#define BC 64

// LDS (ushort elems), single-buffered: 44544 B -> 3 wgs/CU (133632 <= 163840)
#define KS_LD 136
#define VS_LD 72
#define PS_LD 68
#define K0 0
#define V0 8704
#define P0 17920            // 8704 + 128*72
#define SMEM_ELEMS 22272    // + 4*16*68

// ws: ML[16][72][2][64] fp32, then Obf[16][48][64][128] bf16 = 13,172,736 B
#define ML_FLOATS (16 * 72 * 2 * 64)
#define WS_BYTES  ((size_t)ML_FLOATS * 4 + (size_t)16 * 48 * 64 * 128 * 2)

#if __has_builtin(__builtin_amdgcn_exp2f)
#define EXP2F(x) __builtin_amdgcn_exp2f(x)
#else
#define EXP2F(x) exp2f(x)
#endif

template <int CTRL>
__device__ __forceinline__ float dpp_f(float x) {
  int xi = __builtin_bit_cast(int, x);
  int yi = __builtin_amdgcn_update_dpp(xi, xi, CTRL, 0xf, 0xf, false);
  return __builtin_bit_cast(float, yi);
}
__device__ __forceinline__ float rowmax16(float x) {
  x = fmaxf(x, dpp_f<0x128>(x));
  x = fmaxf(x, dpp_f<0x124>(x));
  x = fmaxf(x, dpp_f<0x122>(x));
  x = fmaxf(x, dpp_f<0x121>(x));
  return x;
}
__device__ __forceinline__ float rowsum16(float x) {
  x += dpp_f<0x128>(x);
  x += dpp_f<0x124>(x);
  x += dpp_f<0x122>(x);
  x += dpp_f<0x121>(x);
  return x;
}

__device__ __forceinline__ ushort_t f2bf(float f) {
  uint32_t u = __builtin_bit_cast(uint32_t, f);
  return (ushort_t)((u + 0x8000u) >> 16);
}
__device__ __forceinline__ uint32_t bfpack(float lo, float hi) {
  uint32_t a = __builtin_bit_cast(uint32_t, lo) + 0x8000u;
  uint32_t b = __builtin_bit_cast(uint32_t, hi) + 0x8000u;
  return __builtin_amdgcn_perm(b, a, 0x07060302u);
}
__device__ __forceinline__ float bf2f(uint32_t u16) {
  return __builtin_bit_cast(float, u16 << 16);
}

// One flash chunk over Q rows [rt*64, rt*64+64), key tiles [jt_lo, jt_hi).
// nch==1: normalized store to Out. Else: self-normalized partial; oidx<0 -> Out
// (fp32, chunk 0), oidx>=0 -> bf16 ws slot; (m,l) always to ws ML slot.
__device__ __forceinline__ void process_chunk(
    const float* __restrict__ Q, const float* __restrict__ K,
    const float* __restrict__ Vg, float* __restrict__ Out,
    float* __restrict__ ws, ushort_t* __restrict__ smem,
    int b, int rt, int jt_lo, int jt_hi, int mlimit, int flag,
    int nch, int slot, int oidx) {
  const int tid  = threadIdx.x;
  const int lane = tid & 63;
  const int w    = tid >> 6;
  const int qd   = lane >> 4;
  const int nn   = lane & 15;

  const float c1 = 0.08838834764831845f * 1.4426950408889634f;  // scale*log2e

  const int oct = tid & 15;
  const int j0  = (tid >> 4) * 4;
  const int hh  = nn >> 3;
  const int rb  = 8 * hh;

  const int i0w = rt * 64 + w * 16;
  const size_t koff = (size_t)b * SEQ_M * DIM_D;
  const size_t voff = (size_t)b * SEQ_M * DIM_V;

  // ---- Q fragments, pre-scaled by c1 (folds softmax scale into QK) ----
  short8 qf[4];
  {
    const float* Qb = Q + ((size_t)b * SEQ_N + (size_t)(i0w + nn)) * DIM_D;
    union { short8 v; uint32_t u32[4]; } t;
#pragma unroll
    for (int ks = 0; ks < 4; ++ks) {
      const float* p = Qb + ks * 32 + qd * 8;
      float4 f0 = *(const float4*)p, f1 = *(const float4*)(p + 4);
      t.u32[0] = bfpack(f0.x * c1, f0.y * c1);
      t.u32[1] = bfpack(f0.z * c1, f0.w * c1);
      t.u32[2] = bfpack(f1.x * c1, f1.y * c1);
      t.u32[3] = bfpack(f1.z * c1, f1.w * c1);
      qf[ks] = t.v;
    }
  }

  floatx4 o[8];
#pragma unroll
  for (int vt = 0; vt < 8; ++vt) o[vt] = (floatx4)0.0f;
  float m[4], l[4];
#pragma unroll
  for (int r = 0; r < 4; ++r) { m[r] = -3.0e38f; l[r] = 0.0f; }

  float4 kr[4][2], vr[4][2];   // register prefetch

  auto stage_load = [&](int jt) {
    const int jbase = jt * BC;
#pragma unroll
    for (int r = 0; r < 4; ++r) {
      const float* kp = K  + koff + (size_t)(jbase + j0 + r) * DIM_D + oct * 8;
      kr[r][0] = *(const float4*)kp;  kr[r][1] = *(const float4*)(kp + 4);
      const float* vp = Vg + voff + (size_t)(jbase + j0 + r) * DIM_V + oct * 8;
      vr[r][0] = *(const float4*)vp;  vr[r][1] = *(const float4*)(vp + 4);
    }
  };

  auto stage_write = [&](int jt) {
    const int jbase = jt * BC;
#pragma unroll
    for (int r = 0; r < 4; ++r) {     // K rows, zero padded keys
      uint4 kw;
      kw.x = bfpack(kr[r][0].x, kr[r][0].y);
      kw.y = bfpack(kr[r][0].z, kr[r][0].w);
      kw.z = bfpack(kr[r][1].x, kr[r][1].y);
      kw.w = bfpack(kr[r][1].z, kr[r][1].w);
      if (jbase + j0 + r >= mlimit) kw = make_uint4(0u, 0u, 0u, 0u);
      *(uint4*)(smem + K0 + (j0 + r) * KS_LD + oct * 8) = kw;
    }
    float vc[4][8];
#pragma unroll
    for (int r = 0; r < 4; ++r) {
      vc[r][0]=vr[r][0].x; vc[r][1]=vr[r][0].y; vc[r][2]=vr[r][0].z; vc[r][3]=vr[r][0].w;
      vc[r][4]=vr[r][1].x; vc[r][5]=vr[r][1].y; vc[r][6]=vr[r][1].z; vc[r][7]=vr[r][1].w;
    }
#pragma unroll
    for (int q = 0; q < 8; ++q) {
      const int p = 8 * oct + ((oct + q) & 7);   // bijective V^T row swizzle
      uint2 dv;
      dv.x = bfpack(vc[0][q], vc[1][q]);
      dv.y = bfpack(vc[2][q], vc[3][q]);
      *(uint2*)(smem + V0 + p * VS_LD + j0) = dv;
    }
  };

  stage_load(jt_lo);
  stage_write(jt_lo);
  __syncthreads();

  const int len = jt_hi - jt_lo;
#pragma unroll 1
  for (int t = 0; t < len; ++t) {
    const int jt = jt_lo + t;
    const bool more = (t + 1) < len;
    const int jbase = jt * BC;
    if (more) stage_load(jt + 1);

    // ---- S = Q K^T ----
    floatx4 s[4];
#pragma unroll
    for (int ct = 0; ct < 4; ++ct) s[ct] = (floatx4)0.0f;
#pragma unroll
    for (int ks = 0; ks < 4; ++ks) {
#pragma unroll
      for (int ct = 0; ct < 4; ++ct) {
        short8 bf = *(const short8*)(smem + K0 + (ct * 16 + nn) * KS_LD + ks * 32 + qd * 8);
        s[ct] = __builtin_amdgcn_mfma_f32_16x16x32_bf16(qf[ks], bf, s[ct], 0, 0, 0);
      }
    }

    // ---- online softmax ----
    {
      float tt[4][4];
      if (flag && (jbase + BC - 1 > i0w)) {
#pragma unroll
        for (int ct = 0; ct < 4; ++ct)
#pragma unroll
          for (int r = 0; r < 4; ++r) {
            float tv = s[ct][r];
            if (jbase + ct * 16 + nn > i0w + qd * 4 + r) tv = -3.0e38f;
            tt[ct][r] = tv;
          }
      } else {
#pragma unroll
        for (int ct = 0; ct < 4; ++ct)
#pragma unroll
          for (int r = 0; r < 4; ++r) tt[ct][r] = s[ct][r];
      }
      float mn[4];
#pragma unroll
      for (int r = 0; r < 4; ++r) {
        float mr = fmaxf(fmaxf(tt[0][r], tt[1][r]), fmaxf(tt[2][r], tt[3][r]));
        mr = rowmax16(mr);
        mn[r] = fmaxf(m[r], mr);
      }
      int same = (mn[0] == m[0]) && (mn[1] == m[1]) && (mn[2] == m[2]) && (mn[3] == m[3]);
      if (!__all(same)) {   // wave-uniform: rescale only when some max moved
#pragma unroll
        for (int r = 0; r < 4; ++r) {
          float alpha = EXP2F(m[r] - mn[r]);
          l[r] *= alpha;
#pragma unroll
          for (int vt = 0; vt < 8; ++vt) o[vt][r] *= alpha;
        }
      }
#pragma unroll
      for (int r = 0; r < 4; ++r) {
        m[r] = mn[r];
        float ps = 0.0f;
#pragma unroll
        for (int ct = 0; ct < 4; ++ct) {
          float p = EXP2F(tt[ct][r] - m[r]);
          tt[ct][r] = p;
          ps += p;
        }
        l[r] += ps;
      }
#pragma unroll
      for (int ct = 0; ct < 4; ++ct)
#pragma unroll
        for (int r = 0; r < 4; ++r)
          smem[P0 + (w * 16 + qd * 4 + r) * PS_LD + ct * 16 + nn] = f2bf(tt[ct][r]);
    }

    // ---- O += P V ----
#pragma unroll
    for (int ks2 = 0; ks2 < 2; ++ks2) {
      short8 a = *(const short8*)(smem + P0 + (w * 16 + nn) * PS_LD + ks2 * 32 + qd * 8);
#pragma unroll
      for (int vt = 0; vt < 8; ++vt) {
        const int p = 16 * vt + rb + ((2 * vt + nn + hh) & 7);
        short8 vbf = *(const short8*)(smem + V0 + p * VS_LD + ks2 * 32 + qd * 8);
        o[vt] = __builtin_amdgcn_mfma_f32_16x16x32_bf16(a, vbf, o[vt], 0, 0, 0);
      }
    }

    __syncthreads();                       // all waves done reading K/V
    if (more) { stage_write(jt + 1); __syncthreads(); }
  }

#pragma unroll
  for (int r = 0; r < 4; ++r) l[r] = rowsum16(l[r]);

  // ---- epilogue: self-normalized output; (m,l) to ws for split tiles ----
  if (nch > 1) {
    float* mlp = ws + (size_t)(b * 72 + slot) * 2 * 64;
    if (nn == 0) {
#pragma unroll
      for (int r = 0; r < 4; ++r) {
        int row = w * 16 + qd * 4 + r;
        mlp[row]      = m[r];
        mlp[64 + row] = l[r];
      }
    }
  }
  if (nch == 1 || oidx < 0) {
    float* Ob = Out + ((size_t)b * SEQ_N + i0w) * DIM_V;
#pragma unroll
    for (int r = 0; r < 4; ++r) {
      float inv = 1.0f / l[r];
      int row = qd * 4 + r;
#pragma unroll
      for (int vt = 0; vt < 8; ++vt)
        Ob[(size_t)row * DIM_V + vt * 16 + nn] = o[vt][r] * inv;
    }
  } else {
    ushort_t* ob = (ushort_t*)(ws + ML_FLOATS) + (size_t)(b * 48 + oidx) * 64 * 128;
#pragma unroll
    for (int r = 0; r < 4; ++r) {
      float inv = 1.0f / l[r];
      int row = w * 16 + qd * 4 + r;
#pragma unroll
      for (int vt = 0; vt < 8; ++vt)
        ob[row * 128 + vt * 16 + nn] = f2bf(o[vt][r] * inv);
    }
  }
}

// 1280 chunk wgs (<=8 tiles each), LPT order.
// NOTE: __launch_bounds__(256,2) — NOT 3. Round-7 evidence: (256,3) made LLVM
// allocate 84 VGPRs (6-waves/EU target) and spill the 64-VGPR prefetch arrays
// to scratch (+100 MB HBM traffic). (256,2) compiled this body to 120 VGPR,
// zero spill (round 6); 120 <= 168 still allows 3 waves/EU, LDS allows 3 wg/CU.
__global__ __launch_bounds__(256, 2)
void fa_chunk(const float* __restrict__ Q, const float* __restrict__ K,
              const float* __restrict__ Vg, const int* __restrict__ kpl,
              const int* __restrict__ amask, float* __restrict__ Out,
              float* __restrict__ ws) {
  __shared__ __align__(16) ushort_t smem[SMEM_ELEMS];
  const int u = blockIdx.x;
  const int b = u & 15;
  const int idx = u >> 4;
  const int flag = amask[0];
  const int mlimit = SEQ_M - kpl[b];

  if (flag) {
    int rt, c, nch;
    if (idx < 32)      { rt = 31 - (idx >> 2); c = idx & 3; nch = 4; }
    else if (idx < 56) { int t = idx - 32; int q3 = t / 3; rt = 23 - q3; c = t - 3 * q3; nch = 3; }
    else if (idx < 72) { int t = idx - 56; rt = 15 - (t >> 1); c = t & 1; nch = 2; }
    else               { rt = 79 - idx; c = 0; nch = 1; }
    const int tiles = rt + 1;
    const int lo = (c * tiles) / nch, hi = ((c + 1) * tiles) / nch;
    int slot = 0, oidx = -1;
    if (nch > 1) {
      int sb = (rt >= 24) ? 40 + (rt - 24) * 4 : (rt >= 16) ? 16 + (rt - 16) * 3 : (rt - 8) * 2;
      slot = sb + c;
      if (c > 0)
        oidx = (rt >= 24) ? 24 + (rt - 24) * 3 + (c - 1)
             : (rt >= 16) ? 8 + (rt - 16) * 2 + (c - 1)
                          : (rt - 8) + (c - 1);
    }
    process_chunk(Q, K, Vg, Out, ws, smem, b, rt, lo, hi, mlimit, flag, nch, slot, oidx);
  } else {
    if (u >= 1024) return;
    const int rt = 31 - (idx >> 1), c = idx & 1;
    process_chunk(Q, K, Vg, Out, ws, smem, b, rt, c * 16, c * 16 + 16, mlimit, 0,
                  2, rt * 2 + c, (c > 0) ? rt : -1);
  }
}

// no-ws fallback: 512 whole rows, direct stores
__global__ __launch_bounds__(256, 2)
void fa_whole(const float* __restrict__ Q, const float* __restrict__ K,
              const float* __restrict__ Vg, const int* __restrict__ kpl,
              const int* __restrict__ amask, float* __restrict__ Out) {
  __shared__ __align__(16) ushort_t smem[SMEM_ELEMS];
  const int u = blockIdx.x;
  const int b = u & 15;
  const int idx = u >> 4;
  const int flag = amask[0];
  const int mlimit = SEQ_M - kpl[b];
  int rt = 31 - idx;
  int hi = flag ? (rt + 1) : (SEQ_M / BC);
  process_chunk(Q, K, Vg, Out, nullptr, smem, b, rt, 0, hi, mlimit, flag, 1, 0, -1);
}

__global__ __launch_bounds__(256)
void fa_merge(float* __restrict__ ws, float* __restrict__ Out,
              const int* __restrict__ amask) {
  const int flag = amask[0];
  const int w = threadIdx.x >> 6, lane = threadIdx.x & 63;
  const int rid = blockIdx.x * 4 + w;
  int b, rt, row, nch, sb, ob;
  if (flag) {
    if (rid >= 24576) return;
    b = rid / 1536; int rr = rid - b * 1536;
    rt = 8 + (rr >> 6); row = rr & 63;
    nch = (rt >= 24) ? 4 : (rt >= 16) ? 3 : 2;
    sb  = (rt >= 24) ? 40 + (rt - 24) * 4 : (rt >= 16) ? 16 + (rt - 16) * 3 : (rt - 8) * 2;
    ob  = (rt >= 24) ? 24 + (rt - 24) * 3 : (rt >= 16) ? 8 + (rt - 16) * 2 : (rt - 8);
  } else {
    if (rid >= 32768) return;
    b = rid >> 11; int rr = rid & 2047;
    rt = rr >> 6; row = rr & 63;
    nch = 2; sb = rt * 2; ob = rt;
  }
  float mm[4], ll[4];
  float M = -3.0e38f;
#pragma unroll
  for (int cc = 0; cc < 4; ++cc) if (cc < nch) {
    const float* mlp = ws + (size_t)(b * 72 + sb + cc) * 2 * 64;
    mm[cc] = mlp[row];
    ll[cc] = mlp[64 + row];
    M = fmaxf(M, mm[cc]);
  }
  float wc[4], wsum = 0.0f;
#pragma unroll
  for (int cc = 0; cc < 4; ++cc) if (cc < nch) {
    wc[cc] = ll[cc] * EXP2F(mm[cc] - M);
    wsum += wc[cc];
  }
  const float inv = 1.0f / wsum;
  float* orow = Out + ((size_t)b * SEQ_N + rt * 64 + row) * DIM_V;
  float2 acc = *(float2*)(orow + lane * 2);
  acc.x *= wc[0]; acc.y *= wc[0];
  const ushort_t* Obf = (const ushort_t*)(ws + ML_FLOATS);
#pragma unroll
  for (int cc = 1; cc < 4; ++cc) if (cc < nch) {
    const ushort_t* pr = Obf + ((size_t)(b * 48 + ob + cc - 1) * 64 + row) * 128;
    uint32_t v = *(const uint32_t*)(pr + lane * 2);
    acc.x += bf2f(v & 0xffffu) * wc[cc];
    acc.y += bf2f(v >> 16)     * wc[cc];
  }
  acc.x *= inv; acc.y *= inv;
  *(float2*)(orow + lane * 2) = acc;
}

extern "C" void kernel_launch(void* const* d_in, const int* in_sizes, int n_in,
                              void* d_out, int out_size, void* d_ws, size_t ws_size,
                              hipStream_t stream) {
  const float* Q   = (const float*)d_in[0];
  const float* K   = (const float*)d_in[1];
  const float* V   = (const float*)d_in[2];
  const int* kpl   = (const int*)d_in[3];
  const int* amask = (const int*)d_in[4];
  float* O         = (float*)d_out;
  float* ws        = (float*)d_ws;

  if (ws_size >= WS_BYTES) {
    hipLaunchKernelGGL(fa_chunk, dim3(1280), dim3(256), 0, stream, Q, K, V, kpl, amask, O, ws);
    hipLaunchKernelGGL(fa_merge, dim3(8192), dim3(256), 0, stream, ws, O, amask);
  } else {
    hipLaunchKernelGGL(fa_whole, dim3(512), dim3(256), 0, stream, Q, K, V, kpl, amask, O);
  }
}